// Round 9
// baseline (377.648 us; speedup 1.0000x reference)
//
#include <hip/hip_runtime.h>
#include <cstddef>
#include <cstdint>

typedef __bf16 bf16;
typedef __bf16 bf16x8 __attribute__((ext_vector_type(8)));
typedef float f32x16 __attribute__((ext_vector_type(16)));

#define AS1C(p) ((const __attribute__((address_space(1))) void*)(p))
#define AS3(p)  ((__attribute__((address_space(3))) void*)(p))

#define MROWS 16384
#define HDIM 2560
#define EDIM 1024
#define LSEQ 4096

static __device__ const int kHeadOff[8] = {0, 250007, 500020, 750047,
                                           1000078, 1250115, 1500158, 1750207};

// ------- K1: merged prep: gather E, convert weights, zero S (one launch) ----
__global__ __launch_bounds__(256) void k_prep(const int* __restrict__ hidx,
                                              const float* __restrict__ emb,
                                              bf16* __restrict__ E,
                                              const float* __restrict__ wv,
                                              bf16* __restrict__ wv16,
                                              const float* __restrict__ wk,
                                              bf16* __restrict__ wk16,
                                              float* __restrict__ S) {
  const int b = blockIdx.x;
  const int t = threadIdx.x;
  if (b < 8192) {  // gather: 2 rows/block; 32B read, 16B coalesced write
    const int m = b * 2 + (t >> 7);
    const int tt = t & 127;
    const int head = tt >> 4;
    const int e8 = (tt & 15) * 8;
    const int rid = hidx[m * 8 + head] + kHeadOff[head];
    const float4 v0 = *(const float4*)(emb + (size_t)rid * 128 + e8);
    const float4 v1 = *(const float4*)(emb + (size_t)rid * 128 + e8 + 4);
    bf16x8 o;
    o[0] = (bf16)v0.x; o[1] = (bf16)v0.y; o[2] = (bf16)v0.z; o[3] = (bf16)v0.w;
    o[4] = (bf16)v1.x; o[5] = (bf16)v1.y; o[6] = (bf16)v1.z; o[7] = (bf16)v1.w;
    *(bf16x8*)(E + (size_t)m * EDIM + head * 128 + e8) = o;
  } else if (b < 10752) {  // weight convert (both, 2560 virtual blocks)
    int bb = b - 8192;
    const float* src = wv;
    bf16* dst = wv16;
    if (bb >= 1280) { bb -= 1280; src = wk; dst = wk16; }
    const int i = (bb * 256 + t) * 8;
    const float4 a = *(const float4*)(src + i);
    const float4 c = *(const float4*)(src + i + 4);
    bf16x8 o;
    o[0] = (bf16)a.x; o[1] = (bf16)a.y; o[2] = (bf16)a.z; o[3] = (bf16)a.w;
    o[4] = (bf16)c.x; o[5] = (bf16)c.y; o[6] = (bf16)c.z; o[7] = (bf16)c.w;
    *(bf16x8*)(dst + i) = o;
  } else {  // zero S: 64 blocks x 256 thr x 4 floats = 64K floats
    const int i = ((b - 10752) * 256 + t) * 4;
    *(float4*)(S + i) = float4{0.f, 0.f, 0.f, 0.f};
  }
}

// reduce across 32 lanes (within each 32-lane half)
__device__ __forceinline__ float red32(float v) {
  v += __shfl_xor(v, 1);
  v += __shfl_xor(v, 2);
  v += __shfl_xor(v, 4);
  v += __shfl_xor(v, 8);
  v += __shfl_xor(v, 16);
  return v;
}

// ===== K2: 256x128-tile GEMM, BK=32, 2 blocks/CU, 32x32x16 MFMA =============
// C[m][n] = sum_k A[m][k] * W[n][k];  A=[16384][1024], W=[2560][1024]
// 512 thr = 8 waves (4M x 2N); per-wave out 64x64 = 2x2 of 32x32 frags;
// acc[2][2] f32x16 (64 VGPR).  LDS 48KB: 2 buf x (A 16KB + B 8KB).
// 32x32x16 rate 2495 TF vs 16x16x32's 2176 (m119): +20% matrix pipe, half the
// MFMA instruction count; LDS reads unchanged (8 x 16B per wave-phase).
// A-frag: row=lane&31, k=(lane>>5)*8+j.  C/D: col=lane&31,
// row=(reg&3)+8*(reg>>2)+4*(lane>>5)  [m74/m101].
// Swizzle (64B rows): byte ^= ((row>>1)&3)<<4; source pre-swizzled, dest
// linear; ks*32 col toggle commutes with the XOR ((hi*16)^32 = 32+hi*16).
// R6 loop shell: vmcnt(3) counted, per-tile {begin-barrier; reads; MFMA;
// lgkm0; barrier; stage(p+2)}.  vt blocks: Vt store + S4; kt: S1,S2,S3;
// partials LDS-reduced across wn -> 1 atomic per (row,comp) per block.

#define LDSB 24576  // bytes per buffer: A 16384 + B 8192

__global__ __launch_bounds__(512, 4) void k_gemm(const bf16* __restrict__ A,
                                                 const bf16* __restrict__ Wv,
                                                 const bf16* __restrict__ Wk,
                                                 const float* __restrict__ hidden,
                                                 const float* __restrict__ g_h,
                                                 const float* __restrict__ g_k,
                                                 bf16* __restrict__ Vt,
                                                 float* __restrict__ S) {
  __shared__ __attribute__((aligned(16))) char ldsc[2 * LDSB];
  const int tid = threadIdx.x;
  const int wid = tid >> 6, lane = tid & 63;
  const int wm = wid >> 1, wn = wid & 1;       // 4M x 2N
  const int l31 = lane & 31, hi = lane >> 5;

  // XCD-aware bijective swizzle: 2560 = 8 xcd * 40 gx * 8 y
  const int w = blockIdx.x;
  const int xcd = w & 7;
  const int r_ = w >> 3;                       // 0..319
  const int gx = r_ >> 3;                      // 0..39 column block (slow)
  const int y = xcd * 8 + (r_ & 7);            // row panel (fast)
  const int m0 = y * 256;
  const bool isV = (gx < 20);
  const int n0 = (isV ? gx : gx - 20) * 128;
  const bf16* Wp = isV ? Wv : Wk;

  // read addressing: row-swizzle from l31; ks toggles bit5
  const int sw = ((l31 >> 1) & 3) << 4;
  const int c0s = (hi * 16) ^ sw;              // ks=0 col byte; ks=1 -> ^32
  const int aRd = (wm * 64 + l31) * 64 + c0s;            // + mi*2048 + buf
  const int bRd = 16384 + (wn * 64 + l31) * 64 + c0s;    // + nj*2048 + buf

  // staging source (pre-swizzled): unit = 8KB = 128 rows x 64B
  const int srow = tid >> 2;                   // 0..127 row within unit
  const int scol = (((tid & 3) ^ ((tid >> 3) & 3))) * 8; // element offset
  const bf16* pA0 = A + (size_t)(m0 + srow) * EDIM + scol;
  const bf16* pA1 = pA0 + (size_t)128 * EDIM;
  const bf16* pB = Wp + (size_t)(n0 + srow) * EDIM + scol;
  const int ldsW = wid * 1024;                 // wave slice within unit

  f32x16 acc[2][2] = {};

#define STAGE(BUFO, KT) do {                                                   \
    __builtin_amdgcn_global_load_lds(AS1C(pA0 + (KT) * 32),                    \
        AS3(ldsc + (BUFO) + ldsW), 16, 0, 0);                                  \
    __builtin_amdgcn_global_load_lds(AS1C(pA1 + (KT) * 32),                    \
        AS3(ldsc + (BUFO) + 8192 + ldsW), 16, 0, 0);                           \
    __builtin_amdgcn_global_load_lds(AS1C(pB + (KT) * 32),                     \
        AS3(ldsc + (BUFO) + 16384 + ldsW), 16, 0, 0);                          \
    __builtin_amdgcn_sched_barrier(0);                                         \
  } while (0)

#define PHASE_CORE(BUFO) do {                                                  \
    bf16x8 aF[2][2], bF[2][2];                                                 \
    _Pragma("unroll") for (int mi = 0; mi < 2; ++mi) {                         \
      aF[mi][0] = *(const bf16x8*)(ldsc + (BUFO) + aRd + mi * 2048);           \
      aF[mi][1] = *(const bf16x8*)(ldsc + (BUFO) + (aRd ^ 32) + mi * 2048);    \
    }                                                                          \
    _Pragma("unroll") for (int nj = 0; nj < 2; ++nj) {                         \
      bF[nj][0] = *(const bf16x8*)(ldsc + (BUFO) + bRd + nj * 2048);           \
      bF[nj][1] = *(const bf16x8*)(ldsc + (BUFO) + (bRd ^ 32) + nj * 2048);    \
    }                                                                          \
    __builtin_amdgcn_s_setprio(1);                                             \
    _Pragma("unroll") for (int ks = 0; ks < 2; ++ks)                           \
      _Pragma("unroll") for (int nj = 0; nj < 2; ++nj)                         \
        _Pragma("unroll") for (int mi = 0; mi < 2; ++mi)                       \
          acc[mi][nj] = __builtin_amdgcn_mfma_f32_32x32x16_bf16(               \
              aF[mi][ks], bF[nj][ks], acc[mi][nj], 0, 0, 0);                   \
    __builtin_amdgcn_s_setprio(0);                                             \
    asm volatile("s_waitcnt lgkmcnt(0)" ::: "memory");                         \
    __builtin_amdgcn_s_barrier();                                              \
  } while (0)

#define BEGIN3() do {                                                          \
    asm volatile("s_waitcnt vmcnt(3)" ::: "memory");                           \
    __builtin_amdgcn_s_barrier();                                              \
    asm volatile("" ::: "memory");                                             \
  } while (0)

#define BEGIN0() do {                                                          \
    asm volatile("s_waitcnt vmcnt(0)" ::: "memory");                           \
    __builtin_amdgcn_s_barrier();                                              \
    asm volatile("" ::: "memory");                                             \
  } while (0)

  // prologue: stage tiles 0,1 (6 units in flight)
  STAGE(0, 0);
  STAGE(LDSB, 1);

  for (int p = 0; p < 30; p += 2) {
    BEGIN3();
    PHASE_CORE(0);
    STAGE(0, p + 2);
    BEGIN3();
    PHASE_CORE(LDSB);
    STAGE(LDSB, p + 3);
  }
  BEGIN3();
  PHASE_CORE(0);       // tile 30
  BEGIN0();
  PHASE_CORE(LDSB);    // tile 31 (drain)

  // ---- epilogue.  row = m0+wm*64+mi*32+crow(reg,hi); col = n0+wn*64+nj*32+l31
  float* P = (float*)ldsc;  // free after final barrier
  if (isV) {
#pragma unroll
    for (int mi = 0; mi < 2; ++mi) {
#pragma unroll
      for (int nj = 0; nj < 2; ++nj) {
        const int col = n0 + wn * 64 + nj * 32 + l31;
#pragma unroll
        for (int reg = 0; reg < 16; ++reg) {
          const int row =
              m0 + wm * 64 + mi * 32 + (reg & 3) + 8 * (reg >> 2) + 4 * hi;
          Vt[(size_t)row * HDIM + col] = (bf16)acc[mi][nj][reg];
        }
      }
#pragma unroll
      for (int reg = 0; reg < 16; ++reg) {
        float p = acc[mi][0][reg] * acc[mi][0][reg] +
                  acc[mi][1][reg] * acc[mi][1][reg];
        p = red32(p);
        if (l31 == 0) {
          const int rl =
              wm * 64 + mi * 32 + (reg & 3) + 8 * (reg >> 2) + 4 * hi;
          P[wn * 256 + rl] = p;
        }
      }
    }
    __syncthreads();
    if (tid < 256) {
      const float s = P[tid] + P[256 + tid];
      atomicAdd(&S[(size_t)(m0 + tid) * 4 + 3], s);
    }
  } else {
    const int col0 = n0 + wn * 64 + l31;
    const int col1 = col0 + 32;
    const float ghk0 = g_h[col0] * g_k[col0];
    const float ghk1 = g_h[col1] * g_k[col1];
#pragma unroll
    for (int mi = 0; mi < 2; ++mi) {
#pragma unroll
      for (int reg = 0; reg < 16; ++reg) {
        const int row =
            m0 + wm * 64 + mi * 32 + (reg & 3) + 8 * (reg >> 2) + 4 * hi;
        const float h0 = hidden[(size_t)row * HDIM + col0];
        const float h1 = hidden[(size_t)row * HDIM + col1];
        const float k0 = acc[mi][0][reg], k1 = acc[mi][1][reg];
        float p1 = h0 * h0 + h1 * h1;
        float p2 = h0 * ghk0 * k0 + h1 * ghk1 * k1;
        float p3 = k0 * k0 + k1 * k1;
        p1 = red32(p1); p2 = red32(p2); p3 = red32(p3);
        if (l31 == 0) {
          const int rl =
              wm * 64 + mi * 32 + (reg & 3) + 8 * (reg >> 2) + 4 * hi;
          float* Pr = P + (wn * 256 + rl) * 3;
          Pr[0] = p1; Pr[1] = p2; Pr[2] = p3;
        }
      }
    }
    __syncthreads();
    for (int j = tid; j < 768; j += 512) {
      const int rl = j / 3, c = j % 3;
      const float s = P[j] + P[768 + j];
      atomicAdd(&S[(size_t)(m0 + rl) * 4 + c], s);
    }
  }
#undef STAGE
#undef PHASE_CORE
#undef BEGIN3
#undef BEGIN0
}

// ---- per-row scalars from S (inlined into k_fuse) --------------------------
__device__ __forceinline__ void row_scal(const float* __restrict__ S, int m,
                                         float& alpha, float& av) {
  const float4 s = *(const float4*)(S + (size_t)m * 4);
  const float inv_h = rsqrtf(s.x * (1.f / HDIM) + 1e-6f);
  const float inv_k = rsqrtf(s.z * (1.f / HDIM) + 1e-6f);
  const float dot = s.y * inv_h * inv_k * 0.019764235f;  // 1/sqrt(2560)
  float st = sqrtf(fmaxf(fabsf(dot), 1e-6f));
  st = (dot < 0.f) ? -st : st;
  if (dot == 0.f) st = 0.f;
  alpha = 1.f / (1.f + __expf(-st));
  av = alpha * rsqrtf(alpha * alpha * s.w * (1.f / HDIM) + 1e-6f);
}

// ---------------- K4: fused v_tilde/v_n recompute + conv + SiLU + residuals --
__global__ __launch_bounds__(320) void k_fuse(const float* __restrict__ hidden,
                                              const bf16* __restrict__ Vt,
                                              const float* __restrict__ S,
                                              const float* __restrict__ g_v,
                                              const float* __restrict__ conv_w,
                                              const float* __restrict__ conv_b,
                                              float* __restrict__ out) {
  const int mbase = blockIdx.x * 8;
  const int l0 = mbase & (LSEQ - 1);
  const int t = threadIdx.x;
  const int h0 = t * 8;

  float gv[8], cb[8];
  *(float4*)&gv[0] = *(const float4*)(g_v + h0);
  *(float4*)&gv[4] = *(const float4*)(g_v + h0 + 4);
  *(float4*)&cb[0] = *(const float4*)(conv_b + h0);
  *(float4*)&cb[4] = *(const float4*)(conv_b + h0 + 4);
  float4 cw[8];
#pragma unroll
  for (int i = 0; i < 8; ++i)
    cw[i] = *(const float4*)(conv_w + (size_t)(h0 + i) * 4);

  float win[4][8];
#pragma unroll
  for (int jj = 0; jj < 4; ++jj)
#pragma unroll
    for (int i = 0; i < 8; ++i) win[jj][i] = 0.f;

#pragma unroll
  for (int j = 0; j < 11; ++j) {  // source rows mbase-3 .. mbase+7
    const int lj = l0 - 3 + j;
    const int m = mbase - 3 + j;
    float vtl[8];
    if (lj >= 0) {
      float alpha, av;
      row_scal(S, m, alpha, av);
      const bf16x8 v = *(const bf16x8*)(Vt + (size_t)m * HDIM + h0);
#pragma unroll
      for (int i = 0; i < 8; ++i) {
        const float vt = (float)v[i];
        vtl[i] = alpha * vt;
        win[j & 3][i] = av * vt * gv[i];  // v_n
      }
    } else {
#pragma unroll
      for (int i = 0; i < 8; ++i) { win[j & 3][i] = 0.f; vtl[i] = 0.f; }
    }
    if (j >= 3) {
      const int R = mbase + j - 3;
      const size_t base = (size_t)R * HDIM + h0;
      float hx[8];
      *(float4*)&hx[0] = *(const float4*)(hidden + base);
      *(float4*)&hx[4] = *(const float4*)(hidden + base + 4);
      float o[8];
#pragma unroll
      for (int i = 0; i < 8; ++i) {
        float c = cb[i];
        c += ((const float*)&cw[i])[0] * win[(j - 3) & 3][i];
        c += ((const float*)&cw[i])[1] * win[(j - 2) & 3][i];
        c += ((const float*)&cw[i])[2] * win[(j - 1) & 3][i];
        c += ((const float*)&cw[i])[3] * win[j & 3][i];
        const float y = c / (1.f + __expf(-c));  // silu
        o[i] = hx[i] + y + vtl[i];
      }
      *(float4*)(out + base) = *(float4*)&o[0];
      *(float4*)(out + base + 4) = *(float4*)&o[4];
    }
  }
}

// ---------------- launcher ----------------
extern "C" void kernel_launch(void* const* d_in, const int* in_sizes, int n_in,
                              void* d_out, int out_size, void* d_ws,
                              size_t ws_size, hipStream_t stream) {
  const float* hidden = (const float*)d_in[0];
  const int* hashidx = (const int*)d_in[1];
  const float* emb = (const float*)d_in[2];
  const float* w_v = (const float*)d_in[3];
  const float* w_k = (const float*)d_in[4];
  const float* g_h = (const float*)d_in[5];
  const float* g_k = (const float*)d_in[6];
  const float* g_v = (const float*)d_in[7];
  const float* conv_w = (const float*)d_in[8];
  const float* conv_b = (const float*)d_in[9];
  float* out = (float*)d_out;

  char* w = (char*)d_ws;
  bf16* e16 = (bf16*)w;  w += (size_t)MROWS * EDIM * 2;   // 33.5 MB
  bf16* wv16 = (bf16*)w; w += (size_t)HDIM * EDIM * 2;    // 5.2 MB
  bf16* wk16 = (bf16*)w; w += (size_t)HDIM * EDIM * 2;    // 5.2 MB
  bf16* vt16 = (bf16*)w; w += (size_t)MROWS * HDIM * 2;   // 83.9 MB
  float* S = (float*)w;  w += (size_t)MROWS * 4 * 4;      // 256 KB

  k_prep<<<10816, 256, 0, stream>>>(hashidx, emb, e16, w_v, wv16, w_k, wk16, S);
  k_gemm<<<dim3(2560), 512, 0, stream>>>(e16, wv16, wk16, hidden, g_h, g_k,
                                         vt16, S);
  k_fuse<<<MROWS / 8, 320, 0, stream>>>(hidden, vt16, S, g_v, conv_w, conv_b,
                                        out);
}

// Round 10
// 361.340 us; speedup vs baseline: 1.0451x; 1.0451x over previous
//
#include <hip/hip_runtime.h>
#include <cstddef>
#include <cstdint>

typedef __bf16 bf16;
typedef __bf16 bf16x8 __attribute__((ext_vector_type(8)));
typedef float f32x4 __attribute__((ext_vector_type(4)));

#define AS1C(p) ((const __attribute__((address_space(1))) void*)(p))
#define AS3(p)  ((__attribute__((address_space(3))) void*)(p))

#define MROWS 16384
#define HDIM 2560
#define EDIM 1024
#define LSEQ 4096

static __device__ const int kHeadOff[8] = {0, 250007, 500020, 750047,
                                           1000078, 1250115, 1500158, 1750207};

// ------- K1: merged prep: gather E, convert weights, zero S (one launch) ----
__global__ __launch_bounds__(256) void k_prep(const int* __restrict__ hidx,
                                              const float* __restrict__ emb,
                                              bf16* __restrict__ E,
                                              const float* __restrict__ wv,
                                              bf16* __restrict__ wv16,
                                              const float* __restrict__ wk,
                                              bf16* __restrict__ wk16,
                                              float* __restrict__ S) {
  const int b = blockIdx.x;
  const int t = threadIdx.x;
  if (b < 8192) {  // gather: 2 rows/block; 32B read, 16B coalesced write
    const int m = b * 2 + (t >> 7);
    const int tt = t & 127;
    const int head = tt >> 4;
    const int e8 = (tt & 15) * 8;
    const int rid = hidx[m * 8 + head] + kHeadOff[head];
    const float4 v0 = *(const float4*)(emb + (size_t)rid * 128 + e8);
    const float4 v1 = *(const float4*)(emb + (size_t)rid * 128 + e8 + 4);
    bf16x8 o;
    o[0] = (bf16)v0.x; o[1] = (bf16)v0.y; o[2] = (bf16)v0.z; o[3] = (bf16)v0.w;
    o[4] = (bf16)v1.x; o[5] = (bf16)v1.y; o[6] = (bf16)v1.z; o[7] = (bf16)v1.w;
    *(bf16x8*)(E + (size_t)m * EDIM + head * 128 + e8) = o;
  } else if (b < 10752) {  // weight convert (both, 2560 virtual blocks)
    int bb = b - 8192;
    const float* src = wv;
    bf16* dst = wv16;
    if (bb >= 1280) { bb -= 1280; src = wk; dst = wk16; }
    const int i = (bb * 256 + t) * 8;
    const float4 a = *(const float4*)(src + i);
    const float4 c = *(const float4*)(src + i + 4);
    bf16x8 o;
    o[0] = (bf16)a.x; o[1] = (bf16)a.y; o[2] = (bf16)a.z; o[3] = (bf16)a.w;
    o[4] = (bf16)c.x; o[5] = (bf16)c.y; o[6] = (bf16)c.z; o[7] = (bf16)c.w;
    *(bf16x8*)(dst + i) = o;
  } else {  // zero S
    const int i = ((b - 10752) * 256 + t) * 4;
    *(float4*)(S + i) = float4{0.f, 0.f, 0.f, 0.f};
  }
}

// reduce across the 16 lanes of each khalf group (lane = khalf*16 + r16)
__device__ __forceinline__ float red16(float v) {
  v += __shfl_xor(v, 1);
  v += __shfl_xor(v, 2);
  v += __shfl_xor(v, 4);
  v += __shfl_xor(v, 8);
  return v;
}

// ========= K2: 256x128-tile GEMM (R6 core) + L2-resident-B XCD partition ====
// C[m][n] = sum_k A[m][k] * W[n][k];  A=[16384][1024], W=[2560][1024]
// 512 thr = 8 waves (4M x 2N); per-wave out 64x64; acc[4][4] (64 VGPR).
// LDS 48KB: 2 buf x (A 16KB + B 8KB) -> 2 blocks/CU.
// XCD partition (L3-BW attack): each XCD owns a FIXED set of 5 gx columns
// (B set = 1.25MB, L2-resident forever) and sweeps all 64 y row-panels,
// gx-fast so the 5 concurrent same-y blocks share the A panel via L2.
// L3->L2 traffic: 1.36GB -> ~0.3-0.5GB.  xcd=w&7 (dispatch round-robin),
// s=w>>3, yy=s/5, gg=s%5, gx=xcd*5+gg.  XCD 0-3 = V, 4-7 = K.
// Phase: {vmcnt(3); barrier; 8 ds_read; 16 MFMA (compiler fine-waits);
// lgkm0; barrier; stage(p+2)}.  Swizzle byte ^= ((row>>1)&3)<<4, source
// pre-swizzled, dest linear.  vt: Vt store + S4; kt: S1,S2,S3; partials
// LDS-reduced across wn -> 1 atomic per (row,comp) per block.

#define LDSB 24576  // bytes per buffer: A 16384 + B 8192

__global__ __launch_bounds__(512, 4) void k_gemm(const bf16* __restrict__ A,
                                                 const bf16* __restrict__ Wv,
                                                 const bf16* __restrict__ Wk,
                                                 const float* __restrict__ hidden,
                                                 const float* __restrict__ g_h,
                                                 const float* __restrict__ g_k,
                                                 bf16* __restrict__ Vt,
                                                 float* __restrict__ S) {
  __shared__ __attribute__((aligned(16))) char ldsc[2 * LDSB];
  const int tid = threadIdx.x;
  const int wid = tid >> 6, lane = tid & 63;
  const int wm = wid >> 1, wn = wid & 1;       // 4M x 2N
  const int r16 = lane & 15, khalf = lane >> 4;

  // L2-resident-B partition: xcd owns gx in [xcd*5, xcd*5+5), sweeps y
  const int w = blockIdx.x;
  const int xcd = w & 7;
  const int s = w >> 3;                        // 0..319
  const int yy = s / 5;                        // 0..63 row panel (slow)
  const int gg = s % 5;                        // gx within XCD set (fast)
  const int gx = xcd * 5 + gg;                 // 0..39
  const int m0 = yy * 256;
  const bool isV = (gx < 20);
  const int n0 = (isV ? gx : gx - 20) * 128;
  const bf16* Wp = isV ? Wv : Wk;

  // read addressing (byte offsets into ldsc)
  const int sw = ((r16 >> 1) & 3) << 4;        // row-derived swizzle
  const int c0 = (khalf * 16) ^ sw;
  const int aRd = (wm * 64 + r16) * 64 + c0;             // + mi*1024 + buf
  const int bRd = 16384 + (wn * 64 + r16) * 64 + c0;     // + nj*1024 + buf

  // staging source (pre-swizzled): unit = 8KB = 128 rows x 64B
  const int srow = tid >> 2;                   // 0..127 row within unit
  const int scol = (((tid & 3) ^ ((tid >> 3) & 3))) * 8; // element offset
  const bf16* pA0 = A + (size_t)(m0 + srow) * EDIM + scol;
  const bf16* pA1 = pA0 + (size_t)128 * EDIM;
  const bf16* pB = Wp + (size_t)(n0 + srow) * EDIM + scol;
  const int ldsW = wid * 1024;                 // wave slice within unit

  f32x4 acc[4][4] = {};

#define STAGE(BUFO, KT) do {                                                   \
    __builtin_amdgcn_global_load_lds(AS1C(pA0 + (KT) * 32),                    \
        AS3(ldsc + (BUFO) + ldsW), 16, 0, 0);                                  \
    __builtin_amdgcn_global_load_lds(AS1C(pA1 + (KT) * 32),                    \
        AS3(ldsc + (BUFO) + 8192 + ldsW), 16, 0, 0);                           \
    __builtin_amdgcn_global_load_lds(AS1C(pB + (KT) * 32),                     \
        AS3(ldsc + (BUFO) + 16384 + ldsW), 16, 0, 0);                          \
    __builtin_amdgcn_sched_barrier(0);                                         \
  } while (0)

#define PHASE_CORE(BUFO) do {                                                  \
    bf16x8 aF[4], bF[4];                                                       \
    _Pragma("unroll") for (int mi = 0; mi < 4; ++mi)                           \
      aF[mi] = *(const bf16x8*)(ldsc + (BUFO) + aRd + mi * 1024);              \
    _Pragma("unroll") for (int nj = 0; nj < 4; ++nj)                           \
      bF[nj] = *(const bf16x8*)(ldsc + (BUFO) + bRd + nj * 1024);              \
    __builtin_amdgcn_s_setprio(1);                                             \
    _Pragma("unroll") for (int nj = 0; nj < 4; ++nj)                           \
      _Pragma("unroll") for (int mi = 0; mi < 4; ++mi)                         \
        acc[mi][nj] = __builtin_amdgcn_mfma_f32_16x16x32_bf16(                 \
            aF[mi], bF[nj], acc[mi][nj], 0, 0, 0);                             \
    __builtin_amdgcn_s_setprio(0);                                             \
    asm volatile("s_waitcnt lgkmcnt(0)" ::: "memory");                         \
    __builtin_amdgcn_s_barrier();                                              \
  } while (0)

#define BEGIN3() do {                                                          \
    asm volatile("s_waitcnt vmcnt(3)" ::: "memory");                           \
    __builtin_amdgcn_s_barrier();                                              \
    asm volatile("" ::: "memory");                                             \
  } while (0)

#define BEGIN0() do {                                                          \
    asm volatile("s_waitcnt vmcnt(0)" ::: "memory");                           \
    __builtin_amdgcn_s_barrier();                                              \
    asm volatile("" ::: "memory");                                             \
  } while (0)

  // prologue: stage tiles 0,1 (6 units in flight)
  STAGE(0, 0);
  STAGE(LDSB, 1);

  for (int p = 0; p < 30; p += 2) {
    BEGIN3();
    PHASE_CORE(0);
    STAGE(0, p + 2);
    BEGIN3();
    PHASE_CORE(LDSB);
    STAGE(LDSB, p + 3);
  }
  BEGIN3();
  PHASE_CORE(0);       // tile 30
  BEGIN0();
  PHASE_CORE(LDSB);    // tile 31 (drain)

  // ---- epilogue: row = m0+wm*64+mi*16+khalf*4+r; col = n0+wn*64+nj*16+r16
  float* P = (float*)ldsc;  // free after final barrier
  if (isV) {
#pragma unroll
    for (int mi = 0; mi < 4; ++mi) {
#pragma unroll
      for (int nj = 0; nj < 4; ++nj) {
        const int col = n0 + wn * 64 + nj * 16 + r16;
#pragma unroll
        for (int r = 0; r < 4; ++r) {
          const int row = m0 + wm * 64 + mi * 16 + khalf * 4 + r;
          Vt[(size_t)row * HDIM + col] = (bf16)acc[mi][nj][r];
        }
      }
#pragma unroll
      for (int r = 0; r < 4; ++r) {
        float p = 0.f;
#pragma unroll
        for (int nj = 0; nj < 4; ++nj) p += acc[mi][nj][r] * acc[mi][nj][r];
        p = red16(p);
        if (r16 == 0) {
          const int rl = wm * 64 + mi * 16 + khalf * 4 + r;  // 0..255
          P[wn * 256 + rl] = p;
        }
      }
    }
    __syncthreads();
    if (tid < 256) {
      const float s2 = P[tid] + P[256 + tid];
      atomicAdd(&S[(size_t)(m0 + tid) * 4 + 3], s2);
    }
  } else {
    float ghk[4];
#pragma unroll
    for (int nj = 0; nj < 4; ++nj) {
      const int col = n0 + wn * 64 + nj * 16 + r16;
      ghk[nj] = g_h[col] * g_k[col];
    }
#pragma unroll
    for (int mi = 0; mi < 4; ++mi) {
#pragma unroll
      for (int r = 0; r < 4; ++r) {
        const int row = m0 + wm * 64 + mi * 16 + khalf * 4 + r;
        float p1 = 0.f, p2 = 0.f, p3 = 0.f;
#pragma unroll
        for (int nj = 0; nj < 4; ++nj) {
          const int col = n0 + wn * 64 + nj * 16 + r16;
          const float k = acc[mi][nj][r];
          const float h = hidden[(size_t)row * HDIM + col];
          p1 += h * h;
          p2 += h * ghk[nj] * k;
          p3 += k * k;
        }
        p1 = red16(p1); p2 = red16(p2); p3 = red16(p3);
        if (r16 == 0) {
          const int rl = wm * 64 + mi * 16 + khalf * 4 + r;  // 0..255
          float* Pr = P + (wn * 256 + rl) * 3;
          Pr[0] = p1; Pr[1] = p2; Pr[2] = p3;
        }
      }
    }
    __syncthreads();
    for (int j = tid; j < 768; j += 512) {
      const int rl = j / 3, c = j % 3;
      const float s2 = P[j] + P[768 + j];
      atomicAdd(&S[(size_t)(m0 + rl) * 4 + c], s2);
    }
  }
#undef STAGE
#undef PHASE_CORE
#undef BEGIN3
#undef BEGIN0
}

// ---- per-row scalars from S (inlined into k_fuse) --------------------------
__device__ __forceinline__ void row_scal(const float* __restrict__ S, int m,
                                         float& alpha, float& av) {
  const float4 s = *(const float4*)(S + (size_t)m * 4);
  const float inv_h = rsqrtf(s.x * (1.f / HDIM) + 1e-6f);
  const float inv_k = rsqrtf(s.z * (1.f / HDIM) + 1e-6f);
  const float dot = s.y * inv_h * inv_k * 0.019764235f;  // 1/sqrt(2560)
  float st = sqrtf(fmaxf(fabsf(dot), 1e-6f));
  st = (dot < 0.f) ? -st : st;
  if (dot == 0.f) st = 0.f;
  alpha = 1.f / (1.f + __expf(-st));
  av = alpha * rsqrtf(alpha * alpha * s.w * (1.f / HDIM) + 1e-6f);
}

// ---------------- K4: fused v_tilde/v_n recompute + conv + SiLU + residuals --
__global__ __launch_bounds__(320) void k_fuse(const float* __restrict__ hidden,
                                              const bf16* __restrict__ Vt,
                                              const float* __restrict__ S,
                                              const float* __restrict__ g_v,
                                              const float* __restrict__ conv_w,
                                              const float* __restrict__ conv_b,
                                              float* __restrict__ out) {
  const int mbase = blockIdx.x * 8;
  const int l0 = mbase & (LSEQ - 1);
  const int t = threadIdx.x;
  const int h0 = t * 8;

  float gv[8], cb[8];
  *(float4*)&gv[0] = *(const float4*)(g_v + h0);
  *(float4*)&gv[4] = *(const float4*)(g_v + h0 + 4);
  *(float4*)&cb[0] = *(const float4*)(conv_b + h0);
  *(float4*)&cb[4] = *(const float4*)(conv_b + h0 + 4);
  float4 cw[8];
#pragma unroll
  for (int i = 0; i < 8; ++i)
    cw[i] = *(const float4*)(conv_w + (size_t)(h0 + i) * 4);

  float win[4][8];
#pragma unroll
  for (int jj = 0; jj < 4; ++jj)
#pragma unroll
    for (int i = 0; i < 8; ++i) win[jj][i] = 0.f;

#pragma unroll
  for (int j = 0; j < 11; ++j) {  // source rows mbase-3 .. mbase+7
    const int lj = l0 - 3 + j;
    const int m = mbase - 3 + j;
    float vtl[8];
    if (lj >= 0) {
      float alpha, av;
      row_scal(S, m, alpha, av);
      const bf16x8 v = *(const bf16x8*)(Vt + (size_t)m * HDIM + h0);
#pragma unroll
      for (int i = 0; i < 8; ++i) {
        const float vt = (float)v[i];
        vtl[i] = alpha * vt;
        win[j & 3][i] = av * vt * gv[i];  // v_n
      }
    } else {
#pragma unroll
      for (int i = 0; i < 8; ++i) { win[j & 3][i] = 0.f; vtl[i] = 0.f; }
    }
    if (j >= 3) {
      const int R = mbase + j - 3;
      const size_t base = (size_t)R * HDIM + h0;
      float hx[8];
      *(float4*)&hx[0] = *(const float4*)(hidden + base);
      *(float4*)&hx[4] = *(const float4*)(hidden + base + 4);
      float o[8];
#pragma unroll
      for (int i = 0; i < 8; ++i) {
        float c = cb[i];
        c += ((const float*)&cw[i])[0] * win[(j - 3) & 3][i];
        c += ((const float*)&cw[i])[1] * win[(j - 2) & 3][i];
        c += ((const float*)&cw[i])[2] * win[(j - 1) & 3][i];
        c += ((const float*)&cw[i])[3] * win[j & 3][i];
        const float y = c / (1.f + __expf(-c));  // silu
        o[i] = hx[i] + y + vtl[i];
      }
      *(float4*)(out + base) = *(float4*)&o[0];
      *(float4*)(out + base + 4) = *(float4*)&o[4];
    }
  }
}

// ---------------- launcher ----------------
extern "C" void kernel_launch(void* const* d_in, const int* in_sizes, int n_in,
                              void* d_out, int out_size, void* d_ws,
                              size_t ws_size, hipStream_t stream) {
  const float* hidden = (const float*)d_in[0];
  const int* hashidx = (const int*)d_in[1];
  const float* emb = (const float*)d_in[2];
  const float* w_v = (const float*)d_in[3];
  const float* w_k = (const float*)d_in[4];
  const float* g_h = (const float*)d_in[5];
  const float* g_k = (const float*)d_in[6];
  const float* g_v = (const float*)d_in[7];
  const float* conv_w = (const float*)d_in[8];
  const float* conv_b = (const float*)d_in[9];
  float* out = (float*)d_out;

  char* w = (char*)d_ws;
  bf16* e16 = (bf16*)w;  w += (size_t)MROWS * EDIM * 2;   // 33.5 MB
  bf16* wv16 = (bf16*)w; w += (size_t)HDIM * EDIM * 2;    // 5.2 MB
  bf16* wk16 = (bf16*)w; w += (size_t)HDIM * EDIM * 2;    // 5.2 MB
  bf16* vt16 = (bf16*)w; w += (size_t)MROWS * HDIM * 2;   // 83.9 MB
  float* S = (float*)w;  w += (size_t)MROWS * 4 * 4;      // 256 KB

  k_prep<<<10816, 256, 0, stream>>>(hashidx, emb, e16, w_v, wv16, w_k, wk16, S);
  k_gemm<<<dim3(2560), 512, 0, stream>>>(e16, wv16, wk16, hidden, g_h, g_k,
                                         vt16, S);
  k_fuse<<<MROWS / 8, 320, 0, stream>>>(hidden, vt16, S, g_v, conv_w, conv_b,
                                        out);
}

// Round 11
// 327.626 us; speedup vs baseline: 1.1527x; 1.1029x over previous
//
#include <hip/hip_runtime.h>
#include <cstddef>
#include <cstdint>

typedef __bf16 bf16;
typedef __bf16 bf16x8 __attribute__((ext_vector_type(8)));
typedef float f32x4 __attribute__((ext_vector_type(4)));

#define AS1C(p) ((const __attribute__((address_space(1))) void*)(p))
#define AS3(p)  ((__attribute__((address_space(3))) void*)(p))

#define MROWS 16384
#define HDIM 2560
#define EDIM 1024
#define LSEQ 4096

static __device__ const int kHeadOff[8] = {0, 250007, 500020, 750047,
                                           1000078, 1250115, 1500158, 1750207};

// ------- K1: merged prep: gather E, convert weights, zero S (one launch) ----
__global__ __launch_bounds__(256) void k_prep(const int* __restrict__ hidx,
                                              const float* __restrict__ emb,
                                              bf16* __restrict__ E,
                                              const float* __restrict__ wv,
                                              bf16* __restrict__ wv16,
                                              const float* __restrict__ wk,
                                              bf16* __restrict__ wk16,
                                              float* __restrict__ S) {
  const int b = blockIdx.x;
  const int t = threadIdx.x;
  if (b < 8192) {  // gather: 2 rows/block; 32B read, 16B coalesced write
    const int m = b * 2 + (t >> 7);
    const int tt = t & 127;
    const int head = tt >> 4;
    const int e8 = (tt & 15) * 8;
    const int rid = hidx[m * 8 + head] + kHeadOff[head];
    const float4 v0 = *(const float4*)(emb + (size_t)rid * 128 + e8);
    const float4 v1 = *(const float4*)(emb + (size_t)rid * 128 + e8 + 4);
    bf16x8 o;
    o[0] = (bf16)v0.x; o[1] = (bf16)v0.y; o[2] = (bf16)v0.z; o[3] = (bf16)v0.w;
    o[4] = (bf16)v1.x; o[5] = (bf16)v1.y; o[6] = (bf16)v1.z; o[7] = (bf16)v1.w;
    *(bf16x8*)(E + (size_t)m * EDIM + head * 128 + e8) = o;
  } else if (b < 10752) {  // weight convert (both, 2560 virtual blocks)
    int bb = b - 8192;
    const float* src = wv;
    bf16* dst = wv16;
    if (bb >= 1280) { bb -= 1280; src = wk; dst = wk16; }
    const int i = (bb * 256 + t) * 8;
    const float4 a = *(const float4*)(src + i);
    const float4 c = *(const float4*)(src + i + 4);
    bf16x8 o;
    o[0] = (bf16)a.x; o[1] = (bf16)a.y; o[2] = (bf16)a.z; o[3] = (bf16)a.w;
    o[4] = (bf16)c.x; o[5] = (bf16)c.y; o[6] = (bf16)c.z; o[7] = (bf16)c.w;
    *(bf16x8*)(dst + i) = o;
  } else {  // zero S
    const int i = ((b - 10752) * 256 + t) * 4;
    *(float4*)(S + i) = float4{0.f, 0.f, 0.f, 0.f};
  }
}

// reduce across the 16 lanes of each khalf group (lane = khalf*16 + r16)
__device__ __forceinline__ float red16(float v) {
  v += __shfl_xor(v, 1);
  v += __shfl_xor(v, 2);
  v += __shfl_xor(v, 4);
  v += __shfl_xor(v, 8);
  return v;
}

// ========= K2: 256x128-tile GEMM, BK=32, 2 blocks/CU  (R6 best core) ========
// C[m][n] = sum_k A[m][k] * W[n][k];  A=[16384][1024], W=[2560][1024]
// 512 thr = 8 waves (4M x 2N); per-wave out 64x64; acc[4][4] (64 VGPR).
// LDS 48KB: 2 buf x (A 16KB + B 8KB) -> 2 blocks/CU (co-resident block's
// MFMA absorbs barrier/prologue/epilogue stalls -- R5's proven lever).
// R4 band mapping: xcd=w&7; each XCD owns 8 y-panels (A band L2-resident),
// gx slow / y fast -> per-XCD L3 pulls ~20MB (proven -120us lever).
// Phase: {vmcnt(3); barrier; 8 ds_read; 16 MFMA (compiler fine-grained lgkm
// waits); lgkm0; barrier; stage(p+2)}.  Counted vmcnt: 6 in flight, wait 3.
// Swizzle (64B rows): byte ^= ((row>>1)&3)<<4 (2-way alias free, m136);
// staging source pre-swizzled with same involution, LDS dest linear.
// vt blocks: store Vt bf16 + S4 partials; kt: no store, S1,S2,S3 partials;
// partials LDS-reduced across wn -> 1 atomic per (row,comp) per block.

#define LDSB 24576  // bytes per buffer: A 16384 + B 8192

__global__ __launch_bounds__(512, 4) void k_gemm(const bf16* __restrict__ A,
                                                 const bf16* __restrict__ Wv,
                                                 const bf16* __restrict__ Wk,
                                                 const float* __restrict__ hidden,
                                                 const float* __restrict__ g_h,
                                                 const float* __restrict__ g_k,
                                                 bf16* __restrict__ Vt,
                                                 float* __restrict__ S) {
  __shared__ __attribute__((aligned(16))) char ldsc[2 * LDSB];
  const int tid = threadIdx.x;
  const int wid = tid >> 6, lane = tid & 63;
  const int wm = wid >> 1, wn = wid & 1;       // 4M x 2N
  const int r16 = lane & 15, khalf = lane >> 4;

  // XCD-aware bijective band swizzle: 2560 = 8 xcd * 2 band * 20 gx * 4 y
  const int w = blockIdx.x;
  const int xcd = w & 7;
  const int r_ = w >> 3;                       // 0..319
  const int band = r_ / 80;                    // 0..1
  const int i_ = r_ % 80;
  const int gx = i_ >> 2;                      // 0..19 column block (slow)
  const int y = xcd * 8 + band * 4 + (i_ & 3); // row panel (fast)
  const int m0 = y * 256;
  const bool isV = (gx < 10);
  const int n0 = (isV ? gx : gx - 10) * 256 + 0;  // 256-wide gx pair below
  // NOTE: grid is 2560 blocks of 128-wide columns => re-derive 128-wide n0:
  // keep R6 exact mapping: 40 gx of 128 cols
  const int gx40 = i_ >> 1;                    // 0..39 (unused path guard)
  (void)gx40;
  const int gxc = gx;                          // alias
  (void)gxc;
  // R6 exact: 2560 = 8 xcd * 40 gx * 8 y was R5; R6 used band form with 20 gx
  // of 256 cols? -- R6 used 40 gx of 128: reconstruct exactly:
  // r_ 0..319: gx_ = r_>>3 (0..39), y_ = xcd*8 + (r_&7)
  const int gx_ = r_ >> 3;
  const int y_ = xcd * 8 + (r_ & 7);
  const int m0_ = y_ * 256;
  const bool isV_ = (gx_ < 20);
  const int n0_ = (isV_ ? gx_ : gx_ - 20) * 128;
  const bf16* Wp = isV_ ? Wv : Wk;

  // read addressing (byte offsets into ldsc)
  const int sw = ((r16 >> 1) & 3) << 4;        // row-derived swizzle
  const int c0 = (khalf * 16) ^ sw;
  const int aRd = (wm * 64 + r16) * 64 + c0;             // + mi*1024 + buf
  const int bRd = 16384 + (wn * 64 + r16) * 64 + c0;     // + nj*1024 + buf

  // staging source (pre-swizzled): unit = 8KB = 128 rows x 64B
  const int srow = tid >> 2;                   // 0..127 row within unit
  const int scol = (((tid & 3) ^ ((tid >> 3) & 3))) * 8; // element offset
  const bf16* pA0 = A + (size_t)(m0_ + srow) * EDIM + scol;
  const bf16* pA1 = pA0 + (size_t)128 * EDIM;
  const bf16* pB = Wp + (size_t)(n0_ + srow) * EDIM + scol;
  const int ldsW = wid * 1024;                 // wave slice within unit

  f32x4 acc[4][4] = {};

#define STAGE(BUFO, KT) do {                                                   \
    __builtin_amdgcn_global_load_lds(AS1C(pA0 + (KT) * 32),                    \
        AS3(ldsc + (BUFO) + ldsW), 16, 0, 0);                                  \
    __builtin_amdgcn_global_load_lds(AS1C(pA1 + (KT) * 32),                    \
        AS3(ldsc + (BUFO) + 8192 + ldsW), 16, 0, 0);                           \
    __builtin_amdgcn_global_load_lds(AS1C(pB + (KT) * 32),                     \
        AS3(ldsc + (BUFO) + 16384 + ldsW), 16, 0, 0);                          \
    __builtin_amdgcn_sched_barrier(0);                                         \
  } while (0)

#define PHASE_CORE(BUFO) do {                                                  \
    bf16x8 aF[4], bF[4];                                                       \
    _Pragma("unroll") for (int mi = 0; mi < 4; ++mi)                           \
      aF[mi] = *(const bf16x8*)(ldsc + (BUFO) + aRd + mi * 1024);              \
    _Pragma("unroll") for (int nj = 0; nj < 4; ++nj)                           \
      bF[nj] = *(const bf16x8*)(ldsc + (BUFO) + bRd + nj * 1024);              \
    __builtin_amdgcn_s_setprio(1);                                             \
    _Pragma("unroll") for (int nj = 0; nj < 4; ++nj)                           \
      _Pragma("unroll") for (int mi = 0; mi < 4; ++mi)                         \
        acc[mi][nj] = __builtin_amdgcn_mfma_f32_16x16x32_bf16(                 \
            aF[mi], bF[nj], acc[mi][nj], 0, 0, 0);                             \
    __builtin_amdgcn_s_setprio(0);                                             \
    asm volatile("s_waitcnt lgkmcnt(0)" ::: "memory");                         \
    __builtin_amdgcn_s_barrier();                                              \
  } while (0)

#define BEGIN3() do {                                                          \
    asm volatile("s_waitcnt vmcnt(3)" ::: "memory");                           \
    __builtin_amdgcn_s_barrier();                                              \
    asm volatile("" ::: "memory");                                             \
  } while (0)

#define BEGIN0() do {                                                          \
    asm volatile("s_waitcnt vmcnt(0)" ::: "memory");                           \
    __builtin_amdgcn_s_barrier();                                              \
    asm volatile("" ::: "memory");                                             \
  } while (0)

  // prologue: stage tiles 0,1 (6 units in flight)
  STAGE(0, 0);
  STAGE(LDSB, 1);

  for (int p = 0; p < 30; p += 2) {
    BEGIN3();
    PHASE_CORE(0);
    STAGE(0, p + 2);
    BEGIN3();
    PHASE_CORE(LDSB);
    STAGE(LDSB, p + 3);
  }
  BEGIN3();
  PHASE_CORE(0);       // tile 30
  BEGIN0();
  PHASE_CORE(LDSB);    // tile 31 (drain)

  // ---- epilogue: row = m0_+wm*64+mi*16+khalf*4+r; col = n0_+wn*64+nj*16+r16
  float* P = (float*)ldsc;  // free after final barrier
  if (isV_) {
#pragma unroll
    for (int mi = 0; mi < 4; ++mi) {
#pragma unroll
      for (int nj = 0; nj < 4; ++nj) {
        const int col = n0_ + wn * 64 + nj * 16 + r16;
#pragma unroll
        for (int r = 0; r < 4; ++r) {
          const int row = m0_ + wm * 64 + mi * 16 + khalf * 4 + r;
          Vt[(size_t)row * HDIM + col] = (bf16)acc[mi][nj][r];
        }
      }
#pragma unroll
      for (int r = 0; r < 4; ++r) {
        float p = 0.f;
#pragma unroll
        for (int nj = 0; nj < 4; ++nj) p += acc[mi][nj][r] * acc[mi][nj][r];
        p = red16(p);
        if (r16 == 0) {
          const int rl = wm * 64 + mi * 16 + khalf * 4 + r;  // 0..255
          P[wn * 256 + rl] = p;
        }
      }
    }
    __syncthreads();
    if (tid < 256) {
      const float s2 = P[tid] + P[256 + tid];
      atomicAdd(&S[(size_t)(m0_ + tid) * 4 + 3], s2);
    }
  } else {
    float ghk[4];
#pragma unroll
    for (int nj = 0; nj < 4; ++nj) {
      const int col = n0_ + wn * 64 + nj * 16 + r16;
      ghk[nj] = g_h[col] * g_k[col];
    }
#pragma unroll
    for (int mi = 0; mi < 4; ++mi) {
#pragma unroll
      for (int r = 0; r < 4; ++r) {
        const int row = m0_ + wm * 64 + mi * 16 + khalf * 4 + r;
        float p1 = 0.f, p2 = 0.f, p3 = 0.f;
#pragma unroll
        for (int nj = 0; nj < 4; ++nj) {
          const int col = n0_ + wn * 64 + nj * 16 + r16;
          const float k = acc[mi][nj][r];
          const float h = hidden[(size_t)row * HDIM + col];
          p1 += h * h;
          p2 += h * ghk[nj] * k;
          p3 += k * k;
        }
        p1 = red16(p1); p2 = red16(p2); p3 = red16(p3);
        if (r16 == 0) {
          const int rl = wm * 64 + mi * 16 + khalf * 4 + r;  // 0..255
          float* Pr = P + (wn * 256 + rl) * 3;
          Pr[0] = p1; Pr[1] = p2; Pr[2] = p3;
        }
      }
    }
    __syncthreads();
    for (int j = tid; j < 768; j += 512) {
      const int rl = j / 3, c = j % 3;
      const float s2 = P[j] + P[768 + j];
      atomicAdd(&S[(size_t)(m0_ + rl) * 4 + c], s2);
    }
  }
#undef STAGE
#undef PHASE_CORE
#undef BEGIN3
#undef BEGIN0
}

// ---- per-row scalars from S (inlined into k_fuse) --------------------------
__device__ __forceinline__ void row_scal(const float* __restrict__ S, int m,
                                         float& alpha, float& av) {
  const float4 s = *(const float4*)(S + (size_t)m * 4);
  const float inv_h = rsqrtf(s.x * (1.f / HDIM) + 1e-6f);
  const float inv_k = rsqrtf(s.z * (1.f / HDIM) + 1e-6f);
  const float dot = s.y * inv_h * inv_k * 0.019764235f;  // 1/sqrt(2560)
  float st = sqrtf(fmaxf(fabsf(dot), 1e-6f));
  st = (dot < 0.f) ? -st : st;
  if (dot == 0.f) st = 0.f;
  alpha = 1.f / (1.f + __expf(-st));
  av = alpha * rsqrtf(alpha * alpha * s.w * (1.f / HDIM) + 1e-6f);
}

// ------- K4: fused v_tilde/v_n recompute + conv + SiLU + residuals ----------
// 16 output rows/block (halo amplification 19/16 vs 11/8).
__global__ __launch_bounds__(320) void k_fuse(const float* __restrict__ hidden,
                                              const bf16* __restrict__ Vt,
                                              const float* __restrict__ S,
                                              const float* __restrict__ g_v,
                                              const float* __restrict__ conv_w,
                                              const float* __restrict__ conv_b,
                                              float* __restrict__ out) {
  const int mbase = blockIdx.x * 16;
  const int l0 = mbase & (LSEQ - 1);   // 4096 % 16 == 0: no batch crossing
  const int t = threadIdx.x;
  const int h0 = t * 8;

  float gv[8], cb[8];
  *(float4*)&gv[0] = *(const float4*)(g_v + h0);
  *(float4*)&gv[4] = *(const float4*)(g_v + h0 + 4);
  *(float4*)&cb[0] = *(const float4*)(conv_b + h0);
  *(float4*)&cb[4] = *(const float4*)(conv_b + h0 + 4);
  float4 cw[8];
#pragma unroll
  for (int i = 0; i < 8; ++i)
    cw[i] = *(const float4*)(conv_w + (size_t)(h0 + i) * 4);

  float win[4][8];
#pragma unroll
  for (int jj = 0; jj < 4; ++jj)
#pragma unroll
    for (int i = 0; i < 8; ++i) win[jj][i] = 0.f;

#pragma unroll
  for (int j = 0; j < 19; ++j) {  // source rows mbase-3 .. mbase+15
    const int lj = l0 - 3 + j;
    const int m = mbase - 3 + j;
    float vtl[8];
    if (lj >= 0) {
      float alpha, av;
      row_scal(S, m, alpha, av);
      const bf16x8 v = *(const bf16x8*)(Vt + (size_t)m * HDIM + h0);
#pragma unroll
      for (int i = 0; i < 8; ++i) {
        const float vt = (float)v[i];
        vtl[i] = alpha * vt;
        win[j & 3][i] = av * vt * gv[i];  // v_n
      }
    } else {
#pragma unroll
      for (int i = 0; i < 8; ++i) { win[j & 3][i] = 0.f; vtl[i] = 0.f; }
    }
    if (j >= 3) {
      const int R = mbase + j - 3;
      const size_t base = (size_t)R * HDIM + h0;
      float hx[8];
      *(float4*)&hx[0] = *(const float4*)(hidden + base);
      *(float4*)&hx[4] = *(const float4*)(hidden + base + 4);
      float o[8];
#pragma unroll
      for (int i = 0; i < 8; ++i) {
        float c = cb[i];
        c += ((const float*)&cw[i])[0] * win[(j - 3) & 3][i];
        c += ((const float*)&cw[i])[1] * win[(j - 2) & 3][i];
        c += ((const float*)&cw[i])[2] * win[(j - 1) & 3][i];
        c += ((const float*)&cw[i])[3] * win[j & 3][i];
        const float y = c / (1.f + __expf(-c));  // silu
        o[i] = hx[i] + y + vtl[i];
      }
      *(float4*)(out + base) = *(float4*)&o[0];
      *(float4*)(out + base + 4) = *(float4*)&o[4];
    }
  }
}

// ---------------- launcher ----------------
extern "C" void kernel_launch(void* const* d_in, const int* in_sizes, int n_in,
                              void* d_out, int out_size, void* d_ws,
                              size_t ws_size, hipStream_t stream) {
  const float* hidden = (const float*)d_in[0];
  const int* hashidx = (const int*)d_in[1];
  const float* emb = (const float*)d_in[2];
  const float* w_v = (const float*)d_in[3];
  const float* w_k = (const float*)d_in[4];
  const float* g_h = (const float*)d_in[5];
  const float* g_k = (const float*)d_in[6];
  const float* g_v = (const float*)d_in[7];
  const float* conv_w = (const float*)d_in[8];
  const float* conv_b = (const float*)d_in[9];
  float* out = (float*)d_out;

  char* w = (char*)d_ws;
  bf16* e16 = (bf16*)w;  w += (size_t)MROWS * EDIM * 2;   // 33.5 MB
  bf16* wv16 = (bf16*)w; w += (size_t)HDIM * EDIM * 2;    // 5.2 MB
  bf16* wk16 = (bf16*)w; w += (size_t)HDIM * EDIM * 2;    // 5.2 MB
  bf16* vt16 = (bf16*)w; w += (size_t)MROWS * HDIM * 2;   // 83.9 MB
  float* S = (float*)w;  w += (size_t)MROWS * 4 * 4;      // 256 KB

  k_prep<<<10816, 256, 0, stream>>>(hashidx, emb, e16, w_v, wv16, w_k, wk16, S);
  k_gemm<<<dim3(2560), 512, 0, stream>>>(e16, wv16, wk16, hidden, g_h, g_k,
                                         vt16, S);
  k_fuse<<<MROWS / 16, 320, 0, stream>>>(hidden, vt16, S, g_v, conv_w, conv_b,
                                         out);
}